// Round 1
// baseline (145.403 us; speedup 1.0000x reference)
//
#include <hip/hip_runtime.h>
#include <hip/hip_bf16.h>
#include <stdint.h>

typedef short  short8  __attribute__((ext_vector_type(8)));
typedef float  floatx4 __attribute__((ext_vector_type(4)));

// d_ws byte layout (all bf16 except bias fp32 at end)
#define WS_W0_ROT   0        // [128][32]  natural k-order
#define WS_W0_TRZ   8192
#define WS_W1_ROT   16384    // [128][128] sigma k-order
#define WS_W1_TRZ   49152
#define WS_W2_ROT   81920    // [16][128]  sigma k-order, rows 9..15 zero
#define WS_W2_TRZ   86016    // rows 3..15 zero
#define WS_BIAS     90112    // fp32: [ob0(128) ob1(128) ob2p(16) tb0 tb1 tb2p] = 544

__device__ __forceinline__ unsigned short f2bf_rne(float f) {
    union { float f; unsigned u; } v; v.f = f;
    unsigned r = v.u + 0x7fffu + ((v.u >> 16) & 1u);
    return (unsigned short)(r >> 16);
}

// ---------------- prep: fp32 weights -> bf16 swizzled in ws ----------------
__global__ void prep_kernel(const float* __restrict__ ow0, const float* __restrict__ ow1,
                            const float* __restrict__ ow2, const float* __restrict__ tw0,
                            const float* __restrict__ tw1, const float* __restrict__ tw2,
                            const float* __restrict__ ob0, const float* __restrict__ ob1,
                            const float* __restrict__ ob2, const float* __restrict__ tb0,
                            const float* __restrict__ tb1, const float* __restrict__ tb2,
                            unsigned char* __restrict__ ws)
{
    int t = blockIdx.x * 256 + threadIdx.x;
    unsigned short* w16 = (unsigned short*)ws;
    if (t < 4096) {                      // ow0 natural [n][k]
        w16[t] = f2bf_rne(ow0[t]);
    } else if (t < 8192) {               // tw0
        w16[t] = f2bf_rne(tw0[t - 4096]);
    } else if (t < 24576) {              // ow1 sigma: ws[n][p] = W[n][(p&7)*16 + (p>>3)]
        int i = t - 8192; int n = i >> 7, p = i & 127;
        w16[t] = f2bf_rne(ow1[n * 128 + ((p & 7) << 4) + (p >> 3)]);
    } else if (t < 40960) {              // tw1 sigma
        int i = t - 24576; int n = i >> 7, p = i & 127;
        w16[t] = f2bf_rne(tw1[n * 128 + ((p & 7) << 4) + (p >> 3)]);
    } else if (t < 43008) {              // ow2 sigma, pad n>=9 with 0
        int i = t - 40960; int n = i >> 7, p = i & 127;
        w16[t] = (n < 9) ? f2bf_rne(ow2[n * 128 + ((p & 7) << 4) + (p >> 3)]) : (unsigned short)0;
    } else if (t < 45056) {              // tw2 sigma, pad n>=3 with 0
        int i = t - 43008; int n = i >> 7, p = i & 127;
        w16[t] = (n < 3) ? f2bf_rne(tw2[n * 128 + ((p & 7) << 4) + (p >> 3)]) : (unsigned short)0;
    } else if (t < 45600) {              // biases fp32, padded
        int i = t - 45056;
        float v;
        if      (i < 128) v = ob0[i];
        else if (i < 256) v = ob1[i - 128];
        else if (i < 272) v = (i - 256 < 9) ? ob2[i - 256] : 0.0f;
        else if (i < 400) v = tb0[i - 272];
        else if (i < 528) v = tb1[i - 400];
        else              v = (i - 528 < 3) ? tb2[i - 528] : 0.0f;
        ((float*)(ws + WS_BIAS))[i] = v;
    }
}

// ---------------- main fused kernel ----------------
__device__ __forceinline__ floatx4 mfma16(short8 a, short8 b, floatx4 c) {
    return __builtin_amdgcn_mfma_f32_16x16x32_bf16(a, b, c, 0, 0, 0);
}

__device__ __forceinline__ short8 pack8(floatx4 a, floatx4 b) {
    union { unsigned u[4]; short8 s; } r;
    union { __hip_bfloat162 b2; unsigned u; } c;
    c.b2 = __float22bfloat162_rn(make_float2(a[0], a[1])); r.u[0] = c.u;
    c.b2 = __float22bfloat162_rn(make_float2(a[2], a[3])); r.u[1] = c.u;
    c.b2 = __float22bfloat162_rn(make_float2(b[0], b[1])); r.u[2] = c.u;
    c.b2 = __float22bfloat162_rn(make_float2(b[2], b[3])); r.u[3] = c.u;
    return r.s;
}

// write relu'd bf16 pair (features nt=2*ntp, 2*ntp+1) for 4 rows into h (sigma layout + XOR swizzle)
__device__ __forceinline__ void write_h_pair(char* hb, int q, int ln, int ntp,
                                             floatx4 aA, floatx4 aB) {
    #pragma unroll
    for (int r = 0; r < 4; ++r) {
        float lo = fmaxf(aA[r], 0.0f), hi = fmaxf(aB[r], 0.0f);
        union { __hip_bfloat162 b2; unsigned u; } c;
        c.b2 = __float22bfloat162_rn(make_float2(lo, hi));
        int m = q * 4 + r;
        int w = (ln * 4 + ntp) ^ ((m & 7) << 2);
        *(unsigned*)(hb + m * 256 + w * 4) = c.u;
    }
}

__device__ __forceinline__ void mat3mul(float* C, const float* A, const float* B) {
    #pragma unroll
    for (int i = 0; i < 3; ++i)
        #pragma unroll
        for (int j = 0; j < 3; ++j)
            C[i*3+j] = A[i*3+0]*B[0+j] + A[i*3+1]*B[3+j] + A[i*3+2]*B[6+j];
}

__launch_bounds__(256, 2)
__global__ void fused_main(const float* __restrict__ y,
                           const unsigned char* __restrict__ ws,
                           float* __restrict__ out)
{
    __shared__ __align__(16) unsigned char lds_h[4 * 4096]; // per-wave 16x128 bf16
    __shared__ float lds_stage[256 * 13];                   // per-row 9 omega + 3 trz (stride 13)

    const int tid  = threadIdx.x;
    const int wv   = tid >> 6;
    const int lane = tid & 63;
    const int ln   = lane & 15;
    const int q    = lane >> 4;
    const int mlp  = wv >> 1;   // 0 = rot, 1 = trz
    const int rh   = wv & 1;    // row half (128 rows each)
    const int wgbase = blockIdx.x * 256;

    const int W0_OFF = mlp ? WS_W0_TRZ : WS_W0_ROT;
    const int W1_OFF = mlp ? WS_W1_TRZ : WS_W1_ROT;
    const int W2_OFF = mlp ? WS_W2_TRZ : WS_W2_ROT;
    const float* bias = (const float*)(ws + WS_BIAS) + (mlp ? 272 : 0);

    // ---- load all B-fragments into registers (persistent across 8 groups) ----
    short8 bw0[8], bw1[32], bw2[4];
    #pragma unroll
    for (int nt = 0; nt < 8; ++nt)
        bw0[nt] = *(const short8*)(ws + W0_OFF + ((nt * 16 + ln) * 32 + q * 8) * 2);
    #pragma unroll
    for (int nt = 0; nt < 8; ++nt) {
        #pragma unroll
        for (int s2 = 0; s2 < 4; ++s2)
            bw1[nt * 4 + s2] = *(const short8*)(ws + W1_OFF + ((nt * 16 + ln) * 128 + s2 * 32 + q * 8) * 2);
    }
    #pragma unroll
    for (int s2 = 0; s2 < 4; ++s2)
        bw2[s2] = *(const short8*)(ws + W2_OFF + (ln * 128 + s2 * 32 + q * 8) * 2);

    float b0v[8], b1v[8];
    #pragma unroll
    for (int nt = 0; nt < 8; ++nt) {
        b0v[nt] = bias[nt * 16 + ln];
        b1v[nt] = bias[128 + nt * 16 + ln];
    }
    const float b2v = bias[256 + ln];

    char* hb = (char*)lds_h + wv * 4096;
    const int cb     = mlp ? 9 : 0;
    const int nvalid = mlp ? 3 : 9;

    // ---- MLP over 8 groups of 16 rows ----
    #pragma unroll 1
    for (int g = 0; g < 8; ++g) {
        const int row0 = wgbase + rh * 128 + g * 16;

        // A0 from y (fp32 -> bf16)
        const float* yp = y + (size_t)(row0 + ln) * 64 + mlp * 32 + q * 8;
        floatx4 y0 = *(const floatx4*)yp;
        floatx4 y1 = *(const floatx4*)(yp + 4);
        short8 a0 = pack8(y0, y1);

        // layer 0: 32 -> 128
        #pragma unroll
        for (int ntp = 0; ntp < 4; ++ntp) {
            float bA = b0v[2*ntp], bB = b0v[2*ntp+1];
            floatx4 aA = {bA, bA, bA, bA};
            floatx4 aB = {bB, bB, bB, bB};
            aA = mfma16(a0, bw0[2*ntp],   aA);
            aB = mfma16(a0, bw0[2*ntp+1], aB);
            write_h_pair(hb, q, ln, ntp, aA, aB);
        }

        // A1 fragments (sigma-packed h, XOR swizzle)
        short8 a1[4];
        #pragma unroll
        for (int s2 = 0; s2 < 4; ++s2) {
            int w = (s2 * 16 + q * 4) ^ ((ln & 7) << 2);
            a1[s2] = *(const short8*)(hb + ln * 256 + w * 4);
        }

        // layer 1: 128 -> 128
        #pragma unroll
        for (int ntp = 0; ntp < 4; ++ntp) {
            float bA = b1v[2*ntp], bB = b1v[2*ntp+1];
            floatx4 aA = {bA, bA, bA, bA};
            floatx4 aB = {bB, bB, bB, bB};
            #pragma unroll
            for (int s2 = 0; s2 < 4; ++s2) {
                aA = mfma16(a1[s2], bw1[(2*ntp)   * 4 + s2], aA);
                aB = mfma16(a1[s2], bw1[(2*ntp+1) * 4 + s2], aB);
            }
            write_h_pair(hb, q, ln, ntp, aA, aB);
        }

        // A2 fragments
        short8 a2[4];
        #pragma unroll
        for (int s2 = 0; s2 < 4; ++s2) {
            int w = (s2 * 16 + q * 4) ^ ((ln & 7) << 2);
            a2[s2] = *(const short8*)(hb + ln * 256 + w * 4);
        }

        // layer 2: 128 -> 16 (9 rot / 3 trz valid)
        floatx4 acc = {b2v, b2v, b2v, b2v};
        #pragma unroll
        for (int s2 = 0; s2 < 4; ++s2)
            acc = mfma16(a2[s2], bw2[s2], acc);

        if (ln < nvalid) {
            const int rl = rh * 128 + g * 16 + q * 4;
            #pragma unroll
            for (int r = 0; r < 4; ++r)
                lds_stage[(rl + r) * 13 + cb + ln] = acc[r];
        }
    }

    __syncthreads();

    // ---- expm: one row per lane ----
    const int row_l = wv * 64 + lane;      // 0..255
    const float* st = &lds_stage[row_l * 13];
    float M[9], Rm[9];
    #pragma unroll
    for (int i = 0; i < 9; ++i) M[i] = st[i];
    const float tz0 = st[9], tz1 = st[10], tz2 = st[11];

    float r0 = fabsf(M[0]) + fabsf(M[1]) + fabsf(M[2]);
    float r1 = fabsf(M[3]) + fabsf(M[4]) + fabsf(M[5]);
    float r2 = fabsf(M[6]) + fabsf(M[7]) + fabsf(M[8]);
    float nrm = fmaxf(r0, fmaxf(r1, r2));
    int e; (void)frexpf(nrm, &e);
    int s = e + 1;
    if (s < 0) s = 0;
    if (s > 24) s = 24;
    float sc;
    { union { unsigned u; float f; } cv; cv.u = (unsigned)(127 - s) << 23; sc = cv.f; }
    #pragma unroll
    for (int i = 0; i < 9; ++i) M[i] *= sc;

    // 12-term Taylor via Horner: R = I + M(I + M/2(...))
    #pragma unroll
    for (int i = 0; i < 9; ++i) Rm[i] = 0.0f;
    Rm[0] = Rm[4] = Rm[8] = 1.0f;
    #pragma unroll
    for (int j = 12; j >= 1; --j) {
        float T[9]; mat3mul(T, M, Rm);
        const float inv = 1.0f / (float)j;
        #pragma unroll
        for (int i = 0; i < 9; ++i) Rm[i] = T[i] * inv;
        Rm[0] += 1.0f; Rm[4] += 1.0f; Rm[8] += 1.0f;
    }
    for (int it = 0; it < s; ++it) {
        float T[9]; mat3mul(T, Rm, Rm);
        #pragma unroll
        for (int i = 0; i < 9; ++i) Rm[i] = T[i];
    }

    float* op = out + (size_t)(wgbase + row_l) * 12;
    floatx4 o0 = {Rm[0], Rm[1], Rm[2], Rm[3]};
    floatx4 o1 = {Rm[4], Rm[5], Rm[6], Rm[7]};
    floatx4 o2 = {Rm[8], tz0, tz1, tz2};
    *(floatx4*)(op)     = o0;
    *(floatx4*)(op + 4) = o1;
    *(floatx4*)(op + 8) = o2;
}

extern "C" void kernel_launch(void* const* d_in, const int* in_sizes, int n_in,
                              void* d_out, int out_size, void* d_ws, size_t ws_size,
                              hipStream_t stream)
{
    const float* y = (const float*)d_in[0];
    prep_kernel<<<179, 256, 0, stream>>>(
        (const float*)d_in[1], (const float*)d_in[3], (const float*)d_in[5],
        (const float*)d_in[7], (const float*)d_in[9], (const float*)d_in[11],
        (const float*)d_in[2], (const float*)d_in[4], (const float*)d_in[6],
        (const float*)d_in[8], (const float*)d_in[10], (const float*)d_in[12],
        (unsigned char*)d_ws);
    fused_main<<<512, 256, 0, stream>>>(y, (const unsigned char*)d_ws, (float*)d_out);
}

// Round 2
// 143.665 us; speedup vs baseline: 1.0121x; 1.0121x over previous
//
#include <hip/hip_runtime.h>
#include <hip/hip_bf16.h>
#include <stdint.h>

typedef short  short8  __attribute__((ext_vector_type(8)));
typedef float  floatx4 __attribute__((ext_vector_type(4)));

// d_ws byte layout (all bf16 except bias fp32 at end)
#define WS_W0_ROT   0        // [128][32]  natural k-order
#define WS_W0_TRZ   8192
#define WS_W1_ROT   16384    // [128][128] sigma k-order
#define WS_W1_TRZ   49152
#define WS_W2_ROT   81920    // [16][128]  sigma k-order, rows 9..15 zero
#define WS_W2_TRZ   86016    // rows 3..15 zero
#define WS_BIAS     90112    // fp32: [ob0(128) ob1(128) ob2p(16) tb0 tb1 tb2p] = 544

__device__ __forceinline__ unsigned short f2bf_rne(float f) {
    union { float f; unsigned u; } v; v.f = f;
    unsigned r = v.u + 0x7fffu + ((v.u >> 16) & 1u);
    return (unsigned short)(r >> 16);
}

// ---------------- prep: fp32 weights -> bf16 swizzled in ws ----------------
__global__ void prep_kernel(const float* __restrict__ ow0, const float* __restrict__ ow1,
                            const float* __restrict__ ow2, const float* __restrict__ tw0,
                            const float* __restrict__ tw1, const float* __restrict__ tw2,
                            const float* __restrict__ ob0, const float* __restrict__ ob1,
                            const float* __restrict__ ob2, const float* __restrict__ tb0,
                            const float* __restrict__ tb1, const float* __restrict__ tb2,
                            unsigned char* __restrict__ ws)
{
    int t = blockIdx.x * 256 + threadIdx.x;
    unsigned short* w16 = (unsigned short*)ws;
    if (t < 4096) {                      // ow0 natural [n][k]
        w16[t] = f2bf_rne(ow0[t]);
    } else if (t < 8192) {               // tw0
        w16[t] = f2bf_rne(tw0[t - 4096]);
    } else if (t < 24576) {              // ow1 sigma: ws[n][p] = W[n][(p&7)*16 + (p>>3)]
        int i = t - 8192; int n = i >> 7, p = i & 127;
        w16[t] = f2bf_rne(ow1[n * 128 + ((p & 7) << 4) + (p >> 3)]);
    } else if (t < 40960) {              // tw1 sigma
        int i = t - 24576; int n = i >> 7, p = i & 127;
        w16[t] = f2bf_rne(tw1[n * 128 + ((p & 7) << 4) + (p >> 3)]);
    } else if (t < 43008) {              // ow2 sigma, pad n>=9 with 0
        int i = t - 40960; int n = i >> 7, p = i & 127;
        w16[t] = (n < 9) ? f2bf_rne(ow2[n * 128 + ((p & 7) << 4) + (p >> 3)]) : (unsigned short)0;
    } else if (t < 45056) {              // tw2 sigma, pad n>=3 with 0
        int i = t - 43008; int n = i >> 7, p = i & 127;
        w16[t] = (n < 3) ? f2bf_rne(tw2[n * 128 + ((p & 7) << 4) + (p >> 3)]) : (unsigned short)0;
    } else if (t < 45600) {              // biases fp32, padded
        int i = t - 45056;
        float v;
        if      (i < 128) v = ob0[i];
        else if (i < 256) v = ob1[i - 128];
        else if (i < 272) v = (i - 256 < 9) ? ob2[i - 256] : 0.0f;
        else if (i < 400) v = tb0[i - 272];
        else if (i < 528) v = tb1[i - 400];
        else              v = (i - 528 < 3) ? tb2[i - 528] : 0.0f;
        ((float*)(ws + WS_BIAS))[i] = v;
    }
}

// ---------------- main fused kernel ----------------
__device__ __forceinline__ floatx4 mfma16(short8 a, short8 b, floatx4 c) {
    return __builtin_amdgcn_mfma_f32_16x16x32_bf16(a, b, c, 0, 0, 0);
}

__device__ __forceinline__ short8 pack8(floatx4 a, floatx4 b) {
    union { unsigned u[4]; short8 s; } r;
    union { __hip_bfloat162 b2; unsigned u; } c;
    c.b2 = __float22bfloat162_rn(make_float2(a[0], a[1])); r.u[0] = c.u;
    c.b2 = __float22bfloat162_rn(make_float2(a[2], a[3])); r.u[1] = c.u;
    c.b2 = __float22bfloat162_rn(make_float2(b[0], b[1])); r.u[2] = c.u;
    c.b2 = __float22bfloat162_rn(make_float2(b[2], b[3])); r.u[3] = c.u;
    return r.s;
}

// Write one layer's relu'd output (8 feature-tiles) for this lane's 4 rows
// into h as b128 chunks. h layout: row m (16 rows) x 16 chunks of 16B;
// chunk c of row m stored at chunk' = c ^ (m&15). Lane (ln,q) owns chunk ln
// of rows m = q*4+r (sigma packing: feature nt*16+ln sits at p = ln*8+nt).
__device__ __forceinline__ void write_h_b128(char* hb, int q, int ln,
                                             const floatx4* acc) {
    #pragma unroll
    for (int r = 0; r < 4; ++r) {
        const int m = q * 4 + r;
        union { unsigned u[4]; short8 s; } pk;
        #pragma unroll
        for (int j = 0; j < 4; ++j) {
            float lo = fmaxf(acc[2 * j][r], 0.0f);
            float hi = fmaxf(acc[2 * j + 1][r], 0.0f);
            union { __hip_bfloat162 b2; unsigned u; } c;
            c.b2 = __float22bfloat162_rn(make_float2(lo, hi));
            pk.u[j] = c.u;
        }
        const int cp = ln ^ (m & 15);
        *(short8*)(hb + m * 256 + cp * 16) = pk.s;
    }
}

__device__ __forceinline__ void read_a_b128(const char* hb, int q, int ln, short8* a) {
    #pragma unroll
    for (int s2 = 0; s2 < 4; ++s2) {
        const int cp = (s2 * 4 + q) ^ (ln & 15);
        a[s2] = *(const short8*)(hb + ln * 256 + cp * 16);
    }
}

__device__ __forceinline__ void mat3mul(float* C, const float* A, const float* B) {
    #pragma unroll
    for (int i = 0; i < 3; ++i)
        #pragma unroll
        for (int j = 0; j < 3; ++j)
            C[i*3+j] = A[i*3+0]*B[0+j] + A[i*3+1]*B[3+j] + A[i*3+2]*B[6+j];
}

__launch_bounds__(256, 2)
__global__ void fused_main(const float* __restrict__ y,
                           const unsigned char* __restrict__ ws,
                           float* __restrict__ out)
{
    __shared__ __align__(16) unsigned char lds_h[4][4096]; // per-wave 16x128 bf16 (swizzled)
    __shared__ __align__(16) float lds_stage[256 * 12];    // per-row [9 omega | 3 trz]

    const int tid  = threadIdx.x;
    const int wv   = tid >> 6;
    const int lane = tid & 63;
    const int ln   = lane & 15;
    const int q    = lane >> 4;
    const int mlp  = wv >> 1;   // 0 = rot, 1 = trz
    const int rh   = wv & 1;    // row half (128 rows each)
    const int wgbase = blockIdx.x * 256;

    const int W0_OFF = mlp ? WS_W0_TRZ : WS_W0_ROT;
    const int W1_OFF = mlp ? WS_W1_TRZ : WS_W1_ROT;
    const int W2_OFF = mlp ? WS_W2_TRZ : WS_W2_ROT;
    const float* bias = (const float*)(ws + WS_BIAS) + (mlp ? 272 : 0);

    // ---- persistent B-fragments (44 short8 = 176 VGPRs incl. AGPR file) ----
    short8 bw0[8], bw1[32], bw2[4];
    #pragma unroll
    for (int nt = 0; nt < 8; ++nt)
        bw0[nt] = *(const short8*)(ws + W0_OFF + ((nt * 16 + ln) * 32 + q * 8) * 2);
    #pragma unroll
    for (int nt = 0; nt < 8; ++nt) {
        #pragma unroll
        for (int s2 = 0; s2 < 4; ++s2)
            bw1[nt * 4 + s2] = *(const short8*)(ws + W1_OFF + ((nt * 16 + ln) * 128 + s2 * 32 + q * 8) * 2);
    }
    #pragma unroll
    for (int s2 = 0; s2 < 4; ++s2)
        bw2[s2] = *(const short8*)(ws + W2_OFF + (ln * 128 + s2 * 32 + q * 8) * 2);

    // biases packed as bf162 (layer0, layer1) -> 8 regs
    unsigned b01[8];
    #pragma unroll
    for (int nt = 0; nt < 8; ++nt) {
        union { __hip_bfloat162 b2; unsigned u; } c;
        c.b2 = __float22bfloat162_rn(make_float2(bias[nt * 16 + ln], bias[128 + nt * 16 + ln]));
        b01[nt] = c.u;
    }
    const float b2v = bias[256 + ln];

    char* hb = (char*)lds_h[wv];
    const int cb     = mlp ? 9 : 0;
    const int nvalid = mlp ? 3 : 9;

    // y addressing: row = wgbase + rh*128 + g*16 + ln, col = mlp*32 + q*8
    const float* ybase = y + (size_t)(wgbase + rh * 128) * 64 + mlp * 32 + q * 8;

    // prologue: load + pack group 0
    floatx4 cy0 = *(const floatx4*)(ybase + (size_t)ln * 64);
    floatx4 cy1 = *(const floatx4*)(ybase + (size_t)ln * 64 + 4);
    short8 a0 = pack8(cy0, cy1);

    #pragma unroll 1
    for (int g = 0; g < 8; ++g) {
        // issue next group's y loads NOW (hide HBM latency behind this group)
        const int gn = (g < 7) ? g + 1 : g;
        const float* yp = ybase + (size_t)(gn * 16 + ln) * 64;
        floatx4 ny0 = *(const floatx4*)yp;
        floatx4 ny1 = *(const floatx4*)(yp + 4);

        // ---- layer 0: 32 -> 128 ----
        floatx4 acc[8];
        #pragma unroll
        for (int nt = 0; nt < 8; ++nt) {
            union { __hip_bfloat162 b2; unsigned u; } c; c.u = b01[nt];
            float b = __bfloat162float(c.b2.x);
            floatx4 a = {b, b, b, b};
            acc[nt] = mfma16(a0, bw0[nt], a);
        }
        write_h_b128(hb, q, ln, acc);

        // pack next a0 inside the lgkm-wait window
        a0 = pack8(ny0, ny1);

        short8 a1[4];
        read_a_b128(hb, q, ln, a1);

        // ---- layer 1: 128 -> 128 ----
        #pragma unroll
        for (int nt = 0; nt < 8; ++nt) {
            union { __hip_bfloat162 b2; unsigned u; } c; c.u = b01[nt];
            float b = __bfloat162float(c.b2.y);
            floatx4 a = {b, b, b, b};
            #pragma unroll
            for (int s2 = 0; s2 < 4; ++s2)
                a = mfma16(a1[s2], bw1[nt * 4 + s2], a);
            acc[nt] = a;
        }
        write_h_b128(hb, q, ln, acc);

        short8 a2[4];
        read_a_b128(hb, q, ln, a2);

        // ---- layer 2: 128 -> 16 (9 rot / 3 trz valid) ----
        floatx4 acc2 = {b2v, b2v, b2v, b2v};
        #pragma unroll
        for (int s2 = 0; s2 < 4; ++s2)
            acc2 = mfma16(a2[s2], bw2[s2], acc2);

        if (ln < nvalid) {
            const int rl = rh * 128 + g * 16 + q * 4;
            #pragma unroll
            for (int r = 0; r < 4; ++r)
                lds_stage[(rl + r) * 12 + cb + ln] = acc2[r];
        }
    }

    __syncthreads();

    // ---- expm: one row per thread (256 rows/WG) ----
    {
        float* st = &lds_stage[tid * 12];
        floatx4 m0 = *(floatx4*)(st);
        floatx4 m1 = *(floatx4*)(st + 4);
        floatx4 m2 = *(floatx4*)(st + 8);
        float M[9] = {m0[0], m0[1], m0[2], m0[3], m1[0], m1[1], m1[2], m1[3], m2[0]};
        const float tz0 = m2[1], tz1 = m2[2], tz2 = m2[3];

        float r0 = fabsf(M[0]) + fabsf(M[1]) + fabsf(M[2]);
        float r1 = fabsf(M[3]) + fabsf(M[4]) + fabsf(M[5]);
        float r2 = fabsf(M[6]) + fabsf(M[7]) + fabsf(M[8]);
        float nrm = fmaxf(r0, fmaxf(r1, r2));
        int e; (void)frexpf(nrm, &e);
        int s = e + 1;
        if (s < 0) s = 0;
        if (s > 24) s = 24;
        float sc;
        { union { unsigned u; float f; } cv; cv.u = (unsigned)(127 - s) << 23; sc = cv.f; }
        #pragma unroll
        for (int i = 0; i < 9; ++i) M[i] *= sc;

        float Rm[9];
        #pragma unroll
        for (int i = 0; i < 9; ++i) Rm[i] = 0.0f;
        Rm[0] = Rm[4] = Rm[8] = 1.0f;
        #pragma unroll
        for (int j = 12; j >= 1; --j) {
            float T[9]; mat3mul(T, M, Rm);
            const float inv = 1.0f / (float)j;
            #pragma unroll
            for (int i = 0; i < 9; ++i) Rm[i] = T[i] * inv;
            Rm[0] += 1.0f; Rm[4] += 1.0f; Rm[8] += 1.0f;
        }
        for (int it = 0; it < s; ++it) {
            float T[9]; mat3mul(T, Rm, Rm);
            #pragma unroll
            for (int i = 0; i < 9; ++i) Rm[i] = T[i];
        }

        floatx4 o0 = {Rm[0], Rm[1], Rm[2], Rm[3]};
        floatx4 o1 = {Rm[4], Rm[5], Rm[6], Rm[7]};
        floatx4 o2 = {Rm[8], tz0, tz1, tz2};
        *(floatx4*)(st)     = o0;
        *(floatx4*)(st + 4) = o1;
        *(floatx4*)(st + 8) = o2;
    }

    __syncthreads();

    // ---- fully-coalesced output: 768 contiguous 16B chunks per WG ----
    {
        float* ob = out + (size_t)wgbase * 12;
        #pragma unroll
        for (int k = 0; k < 3; ++k) {
            const int j = k * 256 + tid;
            floatx4 v = *(floatx4*)&lds_stage[j * 4];
            *(floatx4*)(ob + j * 4) = v;
        }
    }
}

extern "C" void kernel_launch(void* const* d_in, const int* in_sizes, int n_in,
                              void* d_out, int out_size, void* d_ws, size_t ws_size,
                              hipStream_t stream)
{
    const float* y = (const float*)d_in[0];
    prep_kernel<<<179, 256, 0, stream>>>(
        (const float*)d_in[1], (const float*)d_in[3], (const float*)d_in[5],
        (const float*)d_in[7], (const float*)d_in[9], (const float*)d_in[11],
        (const float*)d_in[2], (const float*)d_in[4], (const float*)d_in[6],
        (const float*)d_in[8], (const float*)d_in[10], (const float*)d_in[12],
        (unsigned char*)d_ws);
    fused_main<<<512, 256, 0, stream>>>(y, (const unsigned char*)d_ws, (float*)d_out);
}